// Round 2
// baseline (463.701 us; speedup 1.0000x reference)
//
#include <hip/hip_runtime.h>

// SelfAttnHead: B=4, T=2048, E=1024, H=2048. fp32 in/out, bf16 MFMA internally.
// out = softmax_axis1((q q^T / sqrt(H)) * tril) @ v,  q = x Wq + bq, v = x Wv + bv
// attn[q,k] = e[q,k]/s[k] with e = exp(masked logits), masked entries = exp(0) = 1,
// s[k] = column sum (softmax over query axis). Fold 1/s into v: out = E @ (v/s).

#define B_DIM 4
#define T_DIM 2048
#define E_DIM 1024
#define H_DIM 2048

typedef __attribute__((ext_vector_type(8))) short bf16x8;
typedef __attribute__((ext_vector_type(4))) short s16x4;
typedef __attribute__((ext_vector_type(4))) float f32x4;

__device__ __forceinline__ float bf2f(short s) {
  union { float f; unsigned u; } x; x.u = ((unsigned)(unsigned short)s) << 16; return x.f;
}
__device__ __forceinline__ short f2bf(float f) {
  union { float f; unsigned u; } x; x.f = f;
  unsigned r = x.u + 0x7fff + ((x.u >> 16) & 1);  // RNE
  return (short)(r >> 16);
}

__device__ __forceinline__ void gload16(const short* g, short* l) {
  __builtin_amdgcn_global_load_lds(
      (const __attribute__((address_space(1))) void*)g,
      (__attribute__((address_space(3))) void*)l, 16, 0, 0);
}

// C[m,n] = sum_k A[m,k]*B[n,k]  (A:[M,K], B:[N,K] row-major bf16)
// MODE 0: + fp32 bias, bf16 out.
// MODE 1: E=exp(scale*acc) masked (row<col -> 1.0), bf16 out + column-sum atomics.
// MODE 2: fp32 out.
template<int MODE>
__global__ __launch_bounds__(256) void gemm_bt(
    const short* __restrict__ Ag, const short* __restrict__ Bg,
    const float* __restrict__ bias, void* __restrict__ Cg,
    float* __restrict__ colsum,
    int M, int N, int K, long sA, long sB, long sC, float scale)
{
  __shared__ __align__(16) short As[128 * 32];
  __shared__ __align__(16) short Bs[128 * 32];
  __shared__ float csum[128];

  const int t = threadIdx.x;
  const int bx = blockIdx.x, by = blockIdx.y, bz = blockIdx.z;
  const short* A = Ag + (long)bz * sA + (long)by * 128 * K;
  const short* B = Bg + (long)bz * sB + (long)bx * 128 * K;

  const int lane = t & 63;
  const int wave = t >> 6;
  const int wr = wave >> 1, wc = wave & 1;
  const int l16 = lane & 15, kg = lane >> 4;

  if (MODE == 1) { if (t < 128) csum[t] = 0.0f; }

  f32x4 acc[4][4] = {};

  const int r0 = t >> 2, q0 = t & 3;
  const int c1 = t + 256;
  const int r1 = c1 >> 2, q1 = c1 & 3;

  for (int k0 = 0; k0 < K; k0 += 32) {
    __syncthreads();
    gload16(A + (long)r0 * K + (k0 + q0 * 8), &As[t * 8]);
    gload16(A + (long)r1 * K + (k0 + q1 * 8), &As[c1 * 8]);
    gload16(B + (long)r0 * K + (k0 + q0 * 8), &Bs[t * 8]);
    gload16(B + (long)r1 * K + (k0 + q1 * 8), &Bs[c1 * 8]);
    __syncthreads();
    bf16x8 af[4], bfr[4];
#pragma unroll
    for (int mi = 0; mi < 4; ++mi)
      af[mi] = *(const bf16x8*)&As[(wr * 64 + mi * 16 + l16) * 32 + kg * 8];
#pragma unroll
    for (int ni = 0; ni < 4; ++ni)
      bfr[ni] = *(const bf16x8*)&Bs[(wc * 64 + ni * 16 + l16) * 32 + kg * 8];
#pragma unroll
    for (int mi = 0; mi < 4; ++mi)
#pragma unroll
      for (int ni = 0; ni < 4; ++ni)
        acc[mi][ni] = __builtin_amdgcn_mfma_f32_16x16x32_bf16(af[mi], bfr[ni], acc[mi][ni], 0, 0, 0);
  }

  const int rowb = by * 128 + wr * 64 + kg * 4;  // + mi*16 + r
  const int colb = bx * 128 + wc * 64 + l16;     // + ni*16

  if (MODE == 1) {
    short* C = (short*)Cg + (long)bz * sC;
    float ps[4] = {0.f, 0.f, 0.f, 0.f};
#pragma unroll
    for (int mi = 0; mi < 4; ++mi)
#pragma unroll
      for (int ni = 0; ni < 4; ++ni)
#pragma unroll
        for (int r = 0; r < 4; ++r) {
          int row = rowb + mi * 16 + r;
          int col = colb + ni * 16;
          float e = (row >= col) ? __expf(acc[mi][ni][r] * scale) : 1.0f;
          C[(long)row * N + col] = f2bf(e);
          ps[ni] += e;
        }
#pragma unroll
    for (int ni = 0; ni < 4; ++ni)
      atomicAdd(&csum[wc * 64 + ni * 16 + l16], ps[ni]);
    __syncthreads();
    if (t < 128)
      atomicAdd(&colsum[(long)bz * N + bx * 128 + t], csum[t]);
  } else if (MODE == 0) {
    short* C = (short*)Cg + (long)bz * sC;
#pragma unroll
    for (int mi = 0; mi < 4; ++mi)
#pragma unroll
      for (int ni = 0; ni < 4; ++ni) {
        int col = colb + ni * 16;
        float bv = bias ? bias[col] : 0.f;
#pragma unroll
        for (int r = 0; r < 4; ++r) {
          int row = rowb + mi * 16 + r;
          C[(long)row * N + col] = f2bf(acc[mi][ni][r] + bv);
        }
      }
  } else {
    float* C = (float*)Cg + (long)bz * sC;
#pragma unroll
    for (int mi = 0; mi < 4; ++mi)
#pragma unroll
      for (int ni = 0; ni < 4; ++ni) {
        int col = colb + ni * 16;
#pragma unroll
        for (int r = 0; r < 4; ++r) {
          int row = rowb + mi * 16 + r;
          C[(long)row * N + col] = acc[mi][ni][r];
        }
      }
  }
}

// fp32 -> bf16 elementwise (n multiple of 4)
__global__ __launch_bounds__(256) void f32_to_bf16(
    const float* __restrict__ src, short* __restrict__ dst, long n)
{
  long i = ((long)blockIdx.x * blockDim.x + threadIdx.x) * 4;
  if (i < n) {
    const float4 v = *(const float4*)(src + i);
    s16x4 o;
    o.x = f2bf(v.x); o.y = f2bf(v.y); o.z = f2bf(v.z); o.w = f2bf(v.w);
    *(s16x4*)(dst + i) = o;
  }
}

// dst[c][r] = cvt(src[r][c]) * (sums ? 1/sums[r] : 1)
// src: [R, Cn] (fp32 if IN_F32 else bf16)  ->  dst: [Cn, R] bf16
template<bool IN_F32>
__global__ __launch_bounds__(256) void transpose_scale(
    const void* __restrict__ src_, short* __restrict__ dst,
    const float* __restrict__ sums, int R, int Cn, long sSrc, long sDst, long sSum)
{
  __shared__ short tile[64][65];
  const int t = threadIdx.x;
  const int c0 = blockIdx.x * 64;
  const int r0 = blockIdx.y * 64;
  const int bz = blockIdx.z;
  short* d = dst + (long)bz * sDst;
  const int cx = t & 63, ry = t >> 6;
#pragma unroll
  for (int i = 0; i < 16; ++i) {
    int r = ry + i * 4;
    float v;
    if (IN_F32)
      v = ((const float*)src_ + (long)bz * sSrc)[(long)(r0 + r) * Cn + c0 + cx];
    else
      v = bf2f(((const short*)src_ + (long)bz * sSrc)[(long)(r0 + r) * Cn + c0 + cx]);
    if (sums) v *= 1.0f / sums[(long)bz * sSum + r0 + r];
    tile[r][cx] = f2bf(v);
  }
  __syncthreads();
#pragma unroll
  for (int i = 0; i < 16; ++i) {
    int rr = ry + i * 4;
    d[(long)(c0 + rr) * R + r0 + cx] = tile[cx][rr];
  }
}

extern "C" void kernel_launch(void* const* d_in, const int* in_sizes, int n_in,
                              void* d_out, int out_size, void* d_ws, size_t ws_size,
                              hipStream_t stream) {
  const float* x  = (const float*)d_in[0];
  const float* Wq = (const float*)d_in[1];
  const float* bq = (const float*)d_in[2];
  const float* Wv = (const float*)d_in[3];
  const float* bv = (const float*)d_in[4];
  float* out = (float*)d_out;

  // d_ws layout (96 MiB + 32 KiB)
  char* ws = (char*)d_ws;
  short* P      = (short*)(ws);                                   // 32 MiB [B][T][T]
  short* q      = (short*)(ws + (size_t)32 * 1024 * 1024);        // 32 MiB [B*T][H]
  short* v      = (short*)(ws + (size_t)64 * 1024 * 1024);        // 32 MiB [B*T][H]
  float* colsum = (float*)(ws + (size_t)96 * 1024 * 1024);        // 32 KiB [B][T]
  short* vT = q;  // alias: q dead after the scores GEMM

  // d_out (64 MiB) doubles as scratch for the bf16-converted inputs; all dead
  // before the final GEMM overwrites d_out.
  short* xb  = (short*)d_out;                                     // 16 MiB [B*T][E]
  short* WqT = (short*)((char*)d_out + (size_t)16 * 1024 * 1024); //  4 MiB [H][E]
  short* WvT = (short*)((char*)d_out + (size_t)20 * 1024 * 1024); //  4 MiB [H][E]

  const float scale = 0.022097086912079612f;  // 1/sqrt(2048)
  dim3 blk(256);

  hipMemsetAsync(colsum, 0, (size_t)B_DIM * T_DIM * 4, stream);

  // x -> bf16
  f32_to_bf16<<<dim3((B_DIM * T_DIM * E_DIM) / (256 * 4)), blk, 0, stream>>>(
      x, xb, (long)B_DIM * T_DIM * E_DIM);
  // Wq, Wv -> transposed bf16 [H][E]
  transpose_scale<true><<<dim3(H_DIM / 64, E_DIM / 64, 1), blk, 0, stream>>>(
      Wq, WqT, nullptr, E_DIM, H_DIM, 0, 0, 0);
  transpose_scale<true><<<dim3(H_DIM / 64, E_DIM / 64, 1), blk, 0, stream>>>(
      Wv, WvT, nullptr, E_DIM, H_DIM, 0, 0, 0);

  // q = x WqT^T + bq ; v = x WvT^T + bv   (M=8192, N=2048, K=1024)
  gemm_bt<0><<<dim3(H_DIM / 128, (B_DIM * T_DIM) / 128, 1), blk, 0, stream>>>(
      xb, WqT, bq, q, nullptr, B_DIM * T_DIM, H_DIM, E_DIM, 0, 0, 0, 1.f);
  gemm_bt<0><<<dim3(H_DIM / 128, (B_DIM * T_DIM) / 128, 1), blk, 0, stream>>>(
      xb, WvT, bv, v, nullptr, B_DIM * T_DIM, H_DIM, E_DIM, 0, 0, 0, 1.f);

  // E = exp(mask(q q^T)/sqrt(H)) per batch, + column sums (M=N=T, K=H)
  gemm_bt<1><<<dim3(T_DIM / 128, T_DIM / 128, B_DIM), blk, 0, stream>>>(
      q, q, nullptr, P, colsum, T_DIM, T_DIM, H_DIM,
      (long)T_DIM * H_DIM, (long)T_DIM * H_DIM, (long)T_DIM * T_DIM, scale);

  // vT[h][k] = v[k][h] / colsum[k]   per batch
  transpose_scale<false><<<dim3(H_DIM / 64, T_DIM / 64, B_DIM), blk, 0, stream>>>(
      v, vT, colsum, T_DIM, H_DIM, (long)T_DIM * H_DIM, (long)H_DIM * T_DIM, T_DIM);

  // out = E @ v'  (M=T, N=H, K=T) per batch, fp32 out
  gemm_bt<2><<<dim3(H_DIM / 128, T_DIM / 128, B_DIM), blk, 0, stream>>>(
      P, vT, nullptr, out, nullptr, T_DIM, H_DIM, T_DIM,
      (long)T_DIM * T_DIM, (long)H_DIM * T_DIM, (long)T_DIM * H_DIM, 1.f);
}

// Round 3
// 451.121 us; speedup vs baseline: 1.0279x; 1.0279x over previous
//
#include <hip/hip_runtime.h>

// SelfAttnHead: B=4, T=2048, E=1024, H=2048. fp32 in/out, bf16 MFMA internally.
// out = softmax_axis1((q q^T / sqrt(H)) * tril) @ v,  q = x Wq + bq, v = x Wv + bv
// attn[q,k] = e[q,k]/s[k], e = exp(masked logits); masked (q<k) entries = exp(0) = 1.
// s[k] = column sum. Fold 1/s into v' = v/s. Triangular decomposition:
//   out[q,h] = sum_{k<K_end} P[q,k] v'[k,h] + sfx[rt][h],  K_end=(rt+1)*128,
//   sfx[rt][h] = sum_{k>=K_end} v'[k,h]  (the all-ones masked region, E==1).
// Scores GEMM computes only lower-triangular 128x128 tiles (136/256 per batch);
// colsum initialized to 128*(k>>7) to account for skipped all-ones blocks.

#define B_DIM 4
#define T_DIM 2048
#define E_DIM 1024
#define H_DIM 2048

typedef __attribute__((ext_vector_type(8))) short bf16x8;
typedef __attribute__((ext_vector_type(4))) short s16x4;
typedef __attribute__((ext_vector_type(4))) float f32x4;

__device__ __forceinline__ float bf2f(short s) {
  union { float f; unsigned u; } x; x.u = ((unsigned)(unsigned short)s) << 16; return x.f;
}
__device__ __forceinline__ short f2bf(float f) {
  union { float f; unsigned u; } x; x.f = f;
  unsigned r = x.u + 0x7fff + ((x.u >> 16) & 1);  // RNE
  return (short)(r >> 16);
}

__device__ __forceinline__ void gload16(const short* g, short* l) {
  __builtin_amdgcn_global_load_lds(
      (const __attribute__((address_space(1))) void*)g,
      (__attribute__((address_space(3))) void*)l, 16, 0, 0);
}

// C[m,n] = sum_k A[m,k]*B[n,k]  (A:[M,K], B:[N,K] row-major bf16)
// MODE 0: + fp32 bias, bf16 out. grid (N/128, M/128, z).
// MODE 1: lower-triangular tiles only, grid (136, 1, B). E=exp(scale*acc) for
//         row>=col else 1.0; bf16 out + column-sum atomics.
// MODE 2: fp32 out + sfx[rt][col] added; K-loop ends at (rt+1)*128.
//         grid (M/128, N/128, B)  (row tile in x for load-balance interleave).
template<int MODE>
__global__ __launch_bounds__(256) void gemm_bt(
    const short* __restrict__ Ag, const short* __restrict__ Bg,
    const float* __restrict__ bias, void* __restrict__ Cg,
    float* __restrict__ colsum, const float* __restrict__ sfx,
    int M, int N, int K, long sA, long sB, long sC, float scale)
{
  __shared__ __align__(16) short As[128 * 32];
  __shared__ __align__(16) short Bs[128 * 32];
  __shared__ float csum[128];

  const int t = threadIdx.x;
  const int bz = blockIdx.z;

  int rt, ct;
  if (MODE == 1) {
    int idx = blockIdx.x;
    rt = (int)((sqrtf(8.0f * idx + 1.0f) - 1.0f) * 0.5f);
    while ((rt + 1) * (rt + 2) / 2 <= idx) rt++;
    while (rt * (rt + 1) / 2 > idx) rt--;
    ct = idx - rt * (rt + 1) / 2;
  } else if (MODE == 2) {
    rt = blockIdx.x; ct = blockIdx.y;
  } else {
    rt = blockIdx.y; ct = blockIdx.x;
  }

  const short* A = Ag + (long)bz * sA + (long)rt * 128 * K;
  const short* B = Bg + (long)bz * sB + (long)ct * 128 * K;
  const int kEnd = (MODE == 2) ? (rt + 1) * 128 : K;

  const int lane = t & 63;
  const int wave = t >> 6;
  const int wr = wave >> 1, wc = wave & 1;
  const int l16 = lane & 15, kg = lane >> 4;

  if (MODE == 1) { if (t < 128) csum[t] = 0.0f; }

  f32x4 acc[4][4] = {};

  const int r0 = t >> 2, q0 = t & 3;
  const int c1 = t + 256;
  const int r1 = c1 >> 2, q1 = c1 & 3;

  for (int k0 = 0; k0 < kEnd; k0 += 32) {
    __syncthreads();
    gload16(A + (long)r0 * K + (k0 + q0 * 8), &As[t * 8]);
    gload16(A + (long)r1 * K + (k0 + q1 * 8), &As[c1 * 8]);
    gload16(B + (long)r0 * K + (k0 + q0 * 8), &Bs[t * 8]);
    gload16(B + (long)r1 * K + (k0 + q1 * 8), &Bs[c1 * 8]);
    __syncthreads();
    bf16x8 af[4], bfr[4];
#pragma unroll
    for (int mi = 0; mi < 4; ++mi)
      af[mi] = *(const bf16x8*)&As[(wr * 64 + mi * 16 + l16) * 32 + kg * 8];
#pragma unroll
    for (int ni = 0; ni < 4; ++ni)
      bfr[ni] = *(const bf16x8*)&Bs[(wc * 64 + ni * 16 + l16) * 32 + kg * 8];
#pragma unroll
    for (int mi = 0; mi < 4; ++mi)
#pragma unroll
      for (int ni = 0; ni < 4; ++ni)
        acc[mi][ni] = __builtin_amdgcn_mfma_f32_16x16x32_bf16(af[mi], bfr[ni], acc[mi][ni], 0, 0, 0);
  }

  const int rowb = rt * 128 + wr * 64 + kg * 4;  // + mi*16 + r
  const int colb = ct * 128 + wc * 64 + l16;     // + ni*16

  if (MODE == 1) {
    short* C = (short*)Cg + (long)bz * sC;
    float ps[4] = {0.f, 0.f, 0.f, 0.f};
#pragma unroll
    for (int mi = 0; mi < 4; ++mi)
#pragma unroll
      for (int ni = 0; ni < 4; ++ni)
#pragma unroll
        for (int r = 0; r < 4; ++r) {
          int row = rowb + mi * 16 + r;
          int col = colb + ni * 16;
          float e = (row >= col) ? __expf(acc[mi][ni][r] * scale) : 1.0f;
          C[(long)row * N + col] = f2bf(e);
          ps[ni] += e;
        }
#pragma unroll
    for (int ni = 0; ni < 4; ++ni)
      atomicAdd(&csum[wc * 64 + ni * 16 + l16], ps[ni]);
    __syncthreads();
    if (t < 128)
      atomicAdd(&colsum[(long)bz * N + ct * 128 + t], csum[t]);
  } else if (MODE == 0) {
    short* C = (short*)Cg + (long)bz * sC;
#pragma unroll
    for (int mi = 0; mi < 4; ++mi)
#pragma unroll
      for (int ni = 0; ni < 4; ++ni) {
        int col = colb + ni * 16;
        float bv = bias ? bias[col] : 0.f;
#pragma unroll
        for (int r = 0; r < 4; ++r) {
          int row = rowb + mi * 16 + r;
          C[(long)row * N + col] = f2bf(acc[mi][ni][r] + bv);
        }
      }
  } else {
    float* C = (float*)Cg + (long)bz * sC;
    const float* sf = sfx + ((long)bz * 16 + rt) * N;
#pragma unroll
    for (int mi = 0; mi < 4; ++mi)
#pragma unroll
      for (int ni = 0; ni < 4; ++ni) {
        int col = colb + ni * 16;
        float s = sf[col];
#pragma unroll
        for (int r = 0; r < 4; ++r) {
          int row = rowb + mi * 16 + r;
          C[(long)row * N + col] = acc[mi][ni][r] + s;
        }
      }
  }
}

// fp32 -> bf16 elementwise (n multiple of 4)
__global__ __launch_bounds__(256) void f32_to_bf16(
    const float* __restrict__ src, short* __restrict__ dst, long n)
{
  long i = ((long)blockIdx.x * blockDim.x + threadIdx.x) * 4;
  if (i < n) {
    const float4 v = *(const float4*)(src + i);
    s16x4 o;
    o.x = f2bf(v.x); o.y = f2bf(v.y); o.z = f2bf(v.z); o.w = f2bf(v.w);
    *(s16x4*)(dst + i) = o;
  }
}

// dst[c][r] = cvt(src[r][c]) * (sums ? 1/sums[r] : 1)
// src: [R, Cn] (fp32 if IN_F32 else bf16)  ->  dst: [Cn, R] bf16
template<bool IN_F32>
__global__ __launch_bounds__(256) void transpose_scale(
    const void* __restrict__ src_, short* __restrict__ dst,
    const float* __restrict__ sums, int R, int Cn, long sSrc, long sDst, long sSum)
{
  __shared__ short tile[64][65];
  const int t = threadIdx.x;
  const int c0 = blockIdx.x * 64;
  const int r0 = blockIdx.y * 64;
  const int bz = blockIdx.z;
  short* d = dst + (long)bz * sDst;
  const int cx = t & 63, ry = t >> 6;
#pragma unroll
  for (int i = 0; i < 16; ++i) {
    int r = ry + i * 4;
    float v;
    if (IN_F32)
      v = ((const float*)src_ + (long)bz * sSrc)[(long)(r0 + r) * Cn + c0 + cx];
    else
      v = bf2f(((const short*)src_ + (long)bz * sSrc)[(long)(r0 + r) * Cn + c0 + cx]);
    if (sums) v *= 1.0f / sums[(long)bz * sSum + r0 + r];
    tile[r][cx] = f2bf(v);
  }
  __syncthreads();
#pragma unroll
  for (int i = 0; i < 16; ++i) {
    int rr = ry + i * 4;
    d[(long)(c0 + rr) * R + r0 + cx] = tile[cx][rr];
  }
}

// colsum[bz][k] = 128 * (k>>7): contribution of skipped all-ones upper blocks.
__global__ __launch_bounds__(256) void colsum_init(float* __restrict__ colsum)
{
  int i = blockIdx.x * 256 + threadIdx.x;     // over B*T
  int k = i & (T_DIM - 1);
  colsum[i] = 128.0f * (float)(k >> 7);
}

// psum[bz][j][h] = sum_{k in [j*128,(j+1)*128)} v[bz][k][h] / colsum[bz][k]
__global__ __launch_bounds__(256) void block_psum(
    const short* __restrict__ v, const float* __restrict__ colsum,
    float* __restrict__ psum)
{
  const int h = blockIdx.x * 256 + threadIdx.x;
  const int j = blockIdx.y, bz = blockIdx.z;
  const short* vb = v + (long)bz * T_DIM * H_DIM;
  const float* cs = colsum + (long)bz * T_DIM;
  float s = 0.f;
  const int k0 = j * 128;
  for (int k = k0; k < k0 + 128; ++k)
    s += bf2f(vb[(long)k * H_DIM + h]) * (1.0f / cs[k]);
  psum[((long)bz * 16 + j) * H_DIM + h] = s;
}

// sfx[bz][by][h] = sum_{j > by} psum[bz][j][h]   (by=15 -> 0)
__global__ __launch_bounds__(256) void suffix_scan(
    const float* __restrict__ psum, float* __restrict__ sfx)
{
  const int h = blockIdx.x * 256 + threadIdx.x;
  const int bz = blockIdx.z;
  const long base = (long)bz * 16 * H_DIM + h;
  float suf = 0.f;
  sfx[base + 15L * H_DIM] = 0.f;
  for (int j = 15; j >= 1; --j) {
    suf += psum[base + (long)j * H_DIM];
    sfx[base + (long)(j - 1) * H_DIM] = suf;
  }
}

extern "C" void kernel_launch(void* const* d_in, const int* in_sizes, int n_in,
                              void* d_out, int out_size, void* d_ws, size_t ws_size,
                              hipStream_t stream) {
  const float* x  = (const float*)d_in[0];
  const float* Wq = (const float*)d_in[1];
  const float* bq = (const float*)d_in[2];
  const float* Wv = (const float*)d_in[3];
  const float* bv = (const float*)d_in[4];
  float* out = (float*)d_out;

  // d_ws layout (96 MiB + 544 KiB)
  char* ws = (char*)d_ws;
  short* P      = (short*)(ws);                                   // 32 MiB [B][T][T] (lower tiles only)
  short* q      = (short*)(ws + (size_t)32 * 1024 * 1024);        // 32 MiB [B*T][H]
  short* v      = (short*)(ws + (size_t)64 * 1024 * 1024);        // 32 MiB [B*T][H]
  float* colsum = (float*)(ws + (size_t)96 * 1024 * 1024);        // 32 KiB [B][T]
  float* sfx    = (float*)(ws + (size_t)96 * 1024 * 1024 + 32 * 1024);  // 512 KiB [B][16][H]
  short* vT = q;  // alias: q dead after the scores GEMM

  // d_out (64 MiB) doubles as scratch; all dead before PV GEMM writes d_out.
  short* xb   = (short*)d_out;                                     // 16 MiB [B*T][E]
  short* WqT  = (short*)((char*)d_out + (size_t)16 * 1024 * 1024); //  4 MiB [H][E]
  short* WvT  = (short*)((char*)d_out + (size_t)20 * 1024 * 1024); //  4 MiB [H][E]
  float* psum = (float*)((char*)d_out + (size_t)24 * 1024 * 1024); // 512 KiB [B][16][H]

  const float scale = 0.022097086912079612f;  // 1/sqrt(2048)
  dim3 blk(256);

  // x -> bf16; Wq, Wv -> transposed bf16 [H][E]
  f32_to_bf16<<<dim3((B_DIM * T_DIM * E_DIM) / (256 * 4)), blk, 0, stream>>>(
      x, xb, (long)B_DIM * T_DIM * E_DIM);
  transpose_scale<true><<<dim3(H_DIM / 64, E_DIM / 64, 1), blk, 0, stream>>>(
      Wq, WqT, nullptr, E_DIM, H_DIM, 0, 0, 0);
  transpose_scale<true><<<dim3(H_DIM / 64, E_DIM / 64, 1), blk, 0, stream>>>(
      Wv, WvT, nullptr, E_DIM, H_DIM, 0, 0, 0);

  // q = x WqT^T + bq ; v = x WvT^T + bv   (M=8192, N=2048, K=1024)
  gemm_bt<0><<<dim3(H_DIM / 128, (B_DIM * T_DIM) / 128, 1), blk, 0, stream>>>(
      xb, WqT, bq, q, nullptr, nullptr, B_DIM * T_DIM, H_DIM, E_DIM, 0, 0, 0, 1.f);
  gemm_bt<0><<<dim3(H_DIM / 128, (B_DIM * T_DIM) / 128, 1), blk, 0, stream>>>(
      xb, WvT, bv, v, nullptr, nullptr, B_DIM * T_DIM, H_DIM, E_DIM, 0, 0, 0, 1.f);

  // colsum[bz][k] = 128*(k>>7) (skipped upper all-ones blocks)
  colsum_init<<<dim3((B_DIM * T_DIM) / 256), blk, 0, stream>>>(colsum);

  // E = exp(mask(q q^T)/sqrt(H)): lower-triangular tiles only + colsum atomics
  gemm_bt<1><<<dim3(136, 1, B_DIM), blk, 0, stream>>>(
      q, q, nullptr, P, colsum, nullptr, T_DIM, T_DIM, H_DIM,
      (long)T_DIM * H_DIM, (long)T_DIM * H_DIM, (long)T_DIM * T_DIM, scale);

  // vT[h][k] = v[k][h] / colsum[k]   per batch
  transpose_scale<false><<<dim3(H_DIM / 64, T_DIM / 64, B_DIM), blk, 0, stream>>>(
      v, vT, colsum, T_DIM, H_DIM, (long)T_DIM * H_DIM, (long)H_DIM * T_DIM, T_DIM);

  // suffix sums of v' over key blocks: psum then scan
  block_psum<<<dim3(H_DIM / 256, 16, B_DIM), blk, 0, stream>>>(v, colsum, psum);
  suffix_scan<<<dim3(H_DIM / 256, 1, B_DIM), blk, 0, stream>>>(psum, sfx);

  // out = P(:, :K_end) @ v'(:K_end, :) + sfx[rt]   (M=T, N=H, K=T) per batch
  gemm_bt<2><<<dim3(T_DIM / 128, H_DIM / 128, B_DIM), blk, 0, stream>>>(
      P, vT, nullptr, out, nullptr, sfx, T_DIM, H_DIM, T_DIM,
      (long)T_DIM * T_DIM, (long)H_DIM * T_DIM, (long)T_DIM * H_DIM, 1.f);
}

// Round 4
// 387.876 us; speedup vs baseline: 1.1955x; 1.1631x over previous
//
#include <hip/hip_runtime.h>

// SelfAttnHead: B=4, T=2048, E=1024, H=2048. fp32 in/out, bf16 MFMA internally.
// out = softmax_axis1((q q^T / sqrt(H)) * tril) @ v,  q = x Wq + bq, v = x Wv + bv
// attn[q,k] = e[q,k]/s[k], e = exp(masked logits); masked (q<k) entries = exp(0) = 1.
// s[k] = column sum. Fold 1/s into v' = v/s. Triangular decomposition:
//   out[q,h] = sum_{k<K_end} P[q,k] v'[k,h] + sfx[rt][h],  K_end=(rt+1)*128.
// GEMM core: 128x128 tile, BK=64, XOR-swizzled LDS (conflict-free b128 reads),
// global_load_lds width-16 staging.

#define B_DIM 4
#define T_DIM 2048
#define E_DIM 1024
#define H_DIM 2048

typedef __attribute__((ext_vector_type(8))) short bf16x8;
typedef __attribute__((ext_vector_type(4))) short s16x4;
typedef __attribute__((ext_vector_type(4))) float f32x4;

__device__ __forceinline__ float bf2f(short s) {
  union { float f; unsigned u; } x; x.u = ((unsigned)(unsigned short)s) << 16; return x.f;
}
__device__ __forceinline__ short f2bf(float f) {
  union { float f; unsigned u; } x; x.f = f;
  unsigned r = x.u + 0x7fff + ((x.u >> 16) & 1);  // RNE
  return (short)(r >> 16);
}

__device__ __forceinline__ void gload16(const short* g, short* l) {
  __builtin_amdgcn_global_load_lds(
      (const __attribute__((address_space(1))) void*)g,
      (__attribute__((address_space(3))) void*)l, 16, 0, 0);
}

// C[m,n] = sum_k A[m,k]*B[n,k]  (A:[M,K], B:[N,K] row-major bf16)
// MODE 0: fused dual-output projection. grid (N/128, M/128, 1). cols < N/2 ->
//         Cg/bias, cols >= N/2 -> Cg2/bias2 (row stride N/2). bf16 out.
// MODE 1: lower-triangular tiles only, grid (136, 1, B). E=exp(scale*acc) for
//         row>=col else 1.0; bf16 out + column-sum atomics.
// MODE 2: fp32 out + sfx[rt][col] added; K-loop ends at (rt+1)*128.
//         grid (M/128, N/128, B).
template<int MODE>
__global__ __launch_bounds__(256) void gemm_bt(
    const short* __restrict__ Ag, const short* __restrict__ Bg,
    const float* __restrict__ bias, const float* __restrict__ bias2,
    void* __restrict__ Cg, void* __restrict__ Cg2,
    float* __restrict__ colsum, const float* __restrict__ sfx,
    int M, int N, int K, long sA, long sB, long sC, float scale)
{
  __shared__ __align__(16) short As[128 * 64];
  __shared__ __align__(16) short Bs[128 * 64];
  __shared__ float csum[128];

  const int t = threadIdx.x;
  const int bz = blockIdx.z;

  int rt, ct;
  if (MODE == 1) {
    int idx = 135 - blockIdx.x;  // heavy (large-rt) tiles dispatch first
    rt = (int)((sqrtf(8.0f * idx + 1.0f) - 1.0f) * 0.5f);
    while ((rt + 1) * (rt + 2) / 2 <= idx) rt++;
    while (rt * (rt + 1) / 2 > idx) rt--;
    ct = idx - rt * (rt + 1) / 2;
  } else if (MODE == 2) {
    rt = (gridDim.x - 1) - blockIdx.x;  // heavy tiles first
    ct = blockIdx.y;
  } else {
    rt = blockIdx.y; ct = blockIdx.x;
  }

  const short* A = Ag + (long)bz * sA + (long)rt * 128 * K;
  const short* B = Bg + (long)bz * sB + (long)ct * 128 * K;
  const int kEnd = (MODE == 2) ? (rt + 1) * 128 : K;

  const int lane = t & 63;
  const int wave = t >> 6;
  const int wr = wave >> 1, wc = wave & 1;
  const int l16 = lane & 15, kg = lane >> 4;

  if (MODE == 1) { if (t < 128) csum[t] = 0.0f; }

  f32x4 acc[4][4] = {};

  // Staging: 128 rows x 64 cols bf16 per matrix. Thread t, chunk j: element
  // e = j*256+t -> row r = e>>3, LDS 8-elem chunk cl = e&7 holds GLOBAL chunk
  // cg = cl ^ (r&7) (XOR swizzle on the global address; LDS dest stays
  // lane-contiguous as global_load_lds requires).
  for (int k0 = 0; k0 < kEnd; k0 += 64) {
    __syncthreads();
#pragma unroll
    for (int j = 0; j < 4; ++j) {
      const int e = j * 256 + t;
      const int r = e >> 3, cl = e & 7;
      const int cg = cl ^ (r & 7);
      gload16(A + (long)r * K + (k0 + cg * 8), &As[e * 8]);
      gload16(B + (long)r * K + (k0 + cg * 8), &Bs[e * 8]);
    }
    __syncthreads();
#pragma unroll
    for (int kk = 0; kk < 2; ++kk) {
      bf16x8 af[4], bfr[4];
#pragma unroll
      for (int mi = 0; mi < 4; ++mi)
        af[mi] = *(const bf16x8*)&As[(wr * 64 + mi * 16 + l16) * 64 +
                                     ((kk * 4 + kg) ^ (l16 & 7)) * 8];
#pragma unroll
      for (int ni = 0; ni < 4; ++ni)
        bfr[ni] = *(const bf16x8*)&Bs[(wc * 64 + ni * 16 + l16) * 64 +
                                      ((kk * 4 + kg) ^ (l16 & 7)) * 8];
#pragma unroll
      for (int mi = 0; mi < 4; ++mi)
#pragma unroll
        for (int ni = 0; ni < 4; ++ni)
          acc[mi][ni] = __builtin_amdgcn_mfma_f32_16x16x32_bf16(af[mi], bfr[ni], acc[mi][ni], 0, 0, 0);
    }
  }

  const int rowb = rt * 128 + wr * 64 + kg * 4;  // + mi*16 + r
  const int colb = ct * 128 + wc * 64 + l16;     // + ni*16

  if (MODE == 1) {
    short* C = (short*)Cg + (long)bz * sC;
    float ps[4] = {0.f, 0.f, 0.f, 0.f};
#pragma unroll
    for (int mi = 0; mi < 4; ++mi)
#pragma unroll
      for (int ni = 0; ni < 4; ++ni)
#pragma unroll
        for (int r = 0; r < 4; ++r) {
          int row = rowb + mi * 16 + r;
          int col = colb + ni * 16;
          float e = (row >= col) ? __expf(acc[mi][ni][r] * scale) : 1.0f;
          C[(long)row * N + col] = f2bf(e);
          ps[ni] += e;
        }
#pragma unroll
    for (int ni = 0; ni < 4; ++ni)
      atomicAdd(&csum[wc * 64 + ni * 16 + l16], ps[ni]);
    __syncthreads();
    if (t < 128)
      atomicAdd(&colsum[(long)bz * N + ct * 128 + t], csum[t]);
  } else if (MODE == 0) {
    const int Nh = N >> 1;
#pragma unroll
    for (int mi = 0; mi < 4; ++mi)
#pragma unroll
      for (int ni = 0; ni < 4; ++ni) {
        int col = colb + ni * 16;
        short* C = (col < Nh) ? (short*)Cg : (short*)Cg2;
        const float* bp = (col < Nh) ? bias : bias2;
        int c2 = col & (Nh - 1);
        float bv = bp[c2];
#pragma unroll
        for (int r = 0; r < 4; ++r) {
          int row = rowb + mi * 16 + r;
          C[(long)row * Nh + c2] = f2bf(acc[mi][ni][r] + bv);
        }
      }
  } else {
    float* C = (float*)Cg + (long)bz * sC;
    const float* sf = sfx + ((long)bz * 16 + rt) * N;
#pragma unroll
    for (int mi = 0; mi < 4; ++mi)
#pragma unroll
      for (int ni = 0; ni < 4; ++ni) {
        int col = colb + ni * 16;
        float s = sf[col];
#pragma unroll
        for (int r = 0; r < 4; ++r) {
          int row = rowb + mi * 16 + r;
          C[(long)row * N + col] = acc[mi][ni][r] + s;
        }
      }
  }
}

// fp32 -> bf16 elementwise (n multiple of 4)
__global__ __launch_bounds__(256) void f32_to_bf16(
    const float* __restrict__ src, short* __restrict__ dst, long n)
{
  long i = ((long)blockIdx.x * blockDim.x + threadIdx.x) * 4;
  if (i < n) {
    const float4 v = *(const float4*)(src + i);
    s16x4 o;
    o.x = f2bf(v.x); o.y = f2bf(v.y); o.z = f2bf(v.z); o.w = f2bf(v.w);
    *(s16x4*)(dst + i) = o;
  }
}

// dst[c][r] = cvt(src[r][c]) * (sums ? 1/sums[r] : 1)
// src: [R, Cn] (fp32 if IN_F32 else bf16)  ->  dst: [Cn, R] bf16
template<bool IN_F32>
__global__ __launch_bounds__(256) void transpose_scale(
    const void* __restrict__ src_, short* __restrict__ dst,
    const float* __restrict__ sums, int R, int Cn, long sSrc, long sDst, long sSum)
{
  __shared__ short tile[64][65];
  const int t = threadIdx.x;
  const int c0 = blockIdx.x * 64;
  const int r0 = blockIdx.y * 64;
  const int bz = blockIdx.z;
  short* d = dst + (long)bz * sDst;
  const int cx = t & 63, ry = t >> 6;
#pragma unroll
  for (int i = 0; i < 16; ++i) {
    int r = ry + i * 4;
    float v;
    if (IN_F32)
      v = ((const float*)src_ + (long)bz * sSrc)[(long)(r0 + r) * Cn + c0 + cx];
    else
      v = bf2f(((const short*)src_ + (long)bz * sSrc)[(long)(r0 + r) * Cn + c0 + cx]);
    if (sums) v *= 1.0f / sums[(long)bz * sSum + r0 + r];
    tile[r][cx] = f2bf(v);
  }
  __syncthreads();
#pragma unroll
  for (int i = 0; i < 16; ++i) {
    int rr = ry + i * 4;
    d[(long)(c0 + rr) * R + r0 + cx] = tile[cx][rr];
  }
}

// colsum[bz][k] = 128 * (k>>7): contribution of skipped all-ones upper blocks.
__global__ __launch_bounds__(256) void colsum_init(float* __restrict__ colsum)
{
  int i = blockIdx.x * 256 + threadIdx.x;     // over B*T
  int k = i & (T_DIM - 1);
  colsum[i] = 128.0f * (float)(k >> 7);
}

// psum[bz][j][h] = sum_{k in [j*128,(j+1)*128)} v[bz][k][h] / colsum[bz][k]
__global__ __launch_bounds__(256) void block_psum(
    const short* __restrict__ v, const float* __restrict__ colsum,
    float* __restrict__ psum)
{
  const int h = blockIdx.x * 256 + threadIdx.x;
  const int j = blockIdx.y, bz = blockIdx.z;
  const short* vb = v + (long)bz * T_DIM * H_DIM;
  const float* cs = colsum + (long)bz * T_DIM;
  float s = 0.f;
  const int k0 = j * 128;
  for (int k = k0; k < k0 + 128; ++k)
    s += bf2f(vb[(long)k * H_DIM + h]) * (1.0f / cs[k]);
  psum[((long)bz * 16 + j) * H_DIM + h] = s;
}

// sfx[bz][by][h] = sum_{j > by} psum[bz][j][h]   (by=15 -> 0)
__global__ __launch_bounds__(256) void suffix_scan(
    const float* __restrict__ psum, float* __restrict__ sfx)
{
  const int h = blockIdx.x * 256 + threadIdx.x;
  const int bz = blockIdx.z;
  const long base = (long)bz * 16 * H_DIM + h;
  float suf = 0.f;
  sfx[base + 15L * H_DIM] = 0.f;
  for (int j = 15; j >= 1; --j) {
    suf += psum[base + (long)j * H_DIM];
    sfx[base + (long)(j - 1) * H_DIM] = suf;
  }
}

extern "C" void kernel_launch(void* const* d_in, const int* in_sizes, int n_in,
                              void* d_out, int out_size, void* d_ws, size_t ws_size,
                              hipStream_t stream) {
  const float* x  = (const float*)d_in[0];
  const float* Wq = (const float*)d_in[1];
  const float* bq = (const float*)d_in[2];
  const float* Wv = (const float*)d_in[3];
  const float* bv = (const float*)d_in[4];
  float* out = (float*)d_out;

  // d_ws layout (96 MiB + 544 KiB)
  char* ws = (char*)d_ws;
  short* P      = (short*)(ws);                                   // 32 MiB [B][T][T] (lower tiles)
  short* q      = (short*)(ws + (size_t)32 * 1024 * 1024);        // 32 MiB [B*T][H]
  short* v      = (short*)(ws + (size_t)64 * 1024 * 1024);        // 32 MiB [B*T][H]
  float* colsum = (float*)(ws + (size_t)96 * 1024 * 1024);        // 32 KiB [B][T]
  float* sfx    = (float*)(ws + (size_t)96 * 1024 * 1024 + 32 * 1024);  // 512 KiB [B][16][H]
  short* vT = q;  // alias: q dead after the scores GEMM

  // d_out (64 MiB) doubles as scratch; all dead before PV GEMM writes d_out.
  short* xb    = (short*)d_out;                                     // 16 MiB [B*T][E]
  short* WqvT  = (short*)((char*)d_out + (size_t)16 * 1024 * 1024); //  8 MiB [2H][E]
  float* psum  = (float*)((char*)d_out + (size_t)24 * 1024 * 1024); // 512 KiB [B][16][H]

  const float scale = 0.022097086912079612f;  // 1/sqrt(2048)
  dim3 blk(256);

  // x -> bf16; Wq, Wv -> transposed bf16, concatenated [2H][E]
  f32_to_bf16<<<dim3((B_DIM * T_DIM * E_DIM) / (256 * 4)), blk, 0, stream>>>(
      x, xb, (long)B_DIM * T_DIM * E_DIM);
  transpose_scale<true><<<dim3(H_DIM / 64, E_DIM / 64, 1), blk, 0, stream>>>(
      Wq, WqvT, nullptr, E_DIM, H_DIM, 0, 0, 0);
  transpose_scale<true><<<dim3(H_DIM / 64, E_DIM / 64, 1), blk, 0, stream>>>(
      Wv, WqvT + (size_t)H_DIM * E_DIM, nullptr, E_DIM, H_DIM, 0, 0, 0);

  // fused projections: [q | v] = x @ WqvT^T + [bq | bv]  (M=8192, N=4096, K=1024)
  gemm_bt<0><<<dim3((2 * H_DIM) / 128, (B_DIM * T_DIM) / 128, 1), blk, 0, stream>>>(
      xb, WqvT, bq, bv, q, v, nullptr, nullptr,
      B_DIM * T_DIM, 2 * H_DIM, E_DIM, 0, 0, 0, 1.f);

  // colsum[bz][k] = 128*(k>>7) (skipped upper all-ones blocks)
  colsum_init<<<dim3((B_DIM * T_DIM) / 256), blk, 0, stream>>>(colsum);

  // E = exp(mask(q q^T)/sqrt(H)): lower-triangular tiles only + colsum atomics
  gemm_bt<1><<<dim3(136, 1, B_DIM), blk, 0, stream>>>(
      q, q, nullptr, nullptr, P, nullptr, colsum, nullptr, T_DIM, T_DIM, H_DIM,
      (long)T_DIM * H_DIM, (long)T_DIM * H_DIM, (long)T_DIM * T_DIM, scale);

  // vT[h][k] = v[k][h] / colsum[k]   per batch
  transpose_scale<false><<<dim3(H_DIM / 64, T_DIM / 64, B_DIM), blk, 0, stream>>>(
      v, vT, colsum, T_DIM, H_DIM, (long)T_DIM * H_DIM, (long)H_DIM * T_DIM, T_DIM);

  // suffix sums of v' over key blocks: psum then scan
  block_psum<<<dim3(H_DIM / 256, 16, B_DIM), blk, 0, stream>>>(v, colsum, psum);
  suffix_scan<<<dim3(H_DIM / 256, 1, B_DIM), blk, 0, stream>>>(psum, sfx);

  // out = P(:, :K_end) @ v'(:K_end, :) + sfx[rt]   (M=T, N=H, K=T) per batch
  gemm_bt<2><<<dim3(T_DIM / 128, H_DIM / 128, B_DIM), blk, 0, stream>>>(
      P, vT, nullptr, nullptr, out, nullptr, nullptr, sfx, T_DIM, H_DIM, T_DIM,
      (long)T_DIM * T_DIM, (long)H_DIM * T_DIM, (long)T_DIM * H_DIM, 1.f);
}

// Round 5
// 371.514 us; speedup vs baseline: 1.2481x; 1.0440x over previous
//
#include <hip/hip_runtime.h>

// SelfAttnHead: B=4, T=2048, E=1024, H=2048. fp32 in/out, bf16 MFMA internally.
// out = softmax_axis1((q q^T / sqrt(H)) * tril) @ v,  q = x Wq + bq, v = x Wv + bv
// attn[q,k] = e[q,k]/s[k], e = exp(masked logits); masked (q<k) entries = exp(0) = 1.
// s[k] = column sum. Fold 1/s into v' = v/s. Triangular decomposition:
//   out[q,h] = sum_{k<K_end} P[q,k] v'[k,h] + sfx[rt][h],  K_end=(rt+1)*128.
// GEMM core: 128x128 tile, BK=64, XOR-swizzled LDS staging (conflict-free b128),
// global_load_lds width-16, LDS-repacked coalesced bf16 epilogue stores
// (full-cacheline writes -> no write-allocate HBM reads).

#define B_DIM 4
#define T_DIM 2048
#define E_DIM 1024
#define H_DIM 2048

typedef __attribute__((ext_vector_type(8))) short bf16x8;
typedef __attribute__((ext_vector_type(4))) short s16x4;
typedef __attribute__((ext_vector_type(4))) float f32x4;

__device__ __forceinline__ float bf2f(short s) {
  union { float f; unsigned u; } x; x.u = ((unsigned)(unsigned short)s) << 16; return x.f;
}
__device__ __forceinline__ short f2bf(float f) {
  union { float f; unsigned u; } x; x.f = f;
  unsigned r = x.u + 0x7fff + ((x.u >> 16) & 1);  // RNE
  return (short)(r >> 16);
}

__device__ __forceinline__ void gload16(const short* g, short* l) {
  __builtin_amdgcn_global_load_lds(
      (const __attribute__((address_space(1))) void*)g,
      (__attribute__((address_space(3))) void*)l, 16, 0, 0);
}

// C[m,n] = sum_k A[m,k]*B[n,k]  (A:[M,K], B:[N,K] row-major bf16)
// MODE 0: fused dual-output projection. grid (N/128, M/128, 1). 128-col tiles
//         never straddle N/2: ct<N/256 -> Cg/bias else Cg2/bias2. bf16 out.
// MODE 1: lower-triangular tiles only, grid (136, 1, B). E=exp(scale*acc) for
//         row>=col else 1.0; bf16 out + column-sum atomics (diag tile seeds
//         the skipped-upper-blocks constant 128*ct).
// MODE 2: fp32 out + sfx[rt][col] added; K-loop ends at (rt+1)*128.
//         grid (M/128, N/128, B).
template<int MODE>
__global__ __launch_bounds__(256) void gemm_bt(
    const short* __restrict__ Ag, const short* __restrict__ Bg,
    const float* __restrict__ bias, const float* __restrict__ bias2,
    void* __restrict__ Cg, void* __restrict__ Cg2,
    float* __restrict__ colsum, const float* __restrict__ sfx,
    int M, int N, int K, long sA, long sB, long sC, float scale)
{
  __shared__ __align__(16) short lds[128 * 64 * 2];  // As | Bs; reused as Cs
  short* As = lds;
  short* Bs = lds + 128 * 64;
  __shared__ float csum[128];

  const int t = threadIdx.x;
  const int bz = blockIdx.z;

  int rt, ct;
  if (MODE == 1) {
    int idx = 135 - blockIdx.x;  // heavy (large-rt) tiles dispatch first
    rt = (int)((sqrtf(8.0f * idx + 1.0f) - 1.0f) * 0.5f);
    while ((rt + 1) * (rt + 2) / 2 <= idx) rt++;
    while (rt * (rt + 1) / 2 > idx) rt--;
    ct = idx - rt * (rt + 1) / 2;
  } else if (MODE == 2) {
    rt = (gridDim.x - 1) - blockIdx.x;  // heavy tiles first
    ct = blockIdx.y;
  } else {
    rt = blockIdx.y; ct = blockIdx.x;
  }

  const short* A = Ag + (long)bz * sA + (long)rt * 128 * K;
  const short* B = Bg + (long)bz * sB + (long)ct * 128 * K;
  const int kEnd = (MODE == 2) ? (rt + 1) * 128 : K;

  const int lane = t & 63;
  const int wave = t >> 6;
  const int wr = wave >> 1, wc = wave & 1;
  const int l16 = lane & 15, kg = lane >> 4;

  if (MODE == 1) { if (t < 128) csum[t] = (rt == ct) ? 128.0f * ct : 0.0f; }

  f32x4 acc[4][4] = {};

  // Staging: 128 rows x 64 cols bf16 per matrix. XOR swizzle on the global
  // chunk index keeps LDS dest lane-contiguous (global_load_lds constraint)
  // while making the b128 fragment reads conflict-free.
  for (int k0 = 0; k0 < kEnd; k0 += 64) {
    __syncthreads();
#pragma unroll
    for (int j = 0; j < 4; ++j) {
      const int e = j * 256 + t;
      const int r = e >> 3, cl = e & 7;
      const int cg = cl ^ (r & 7);
      gload16(A + (long)r * K + (k0 + cg * 8), &As[e * 8]);
      gload16(B + (long)r * K + (k0 + cg * 8), &Bs[e * 8]);
    }
    __syncthreads();
#pragma unroll
    for (int kk = 0; kk < 2; ++kk) {
      bf16x8 af[4], bfr[4];
#pragma unroll
      for (int mi = 0; mi < 4; ++mi)
        af[mi] = *(const bf16x8*)&As[(wr * 64 + mi * 16 + l16) * 64 +
                                     ((kk * 4 + kg) ^ (l16 & 7)) * 8];
#pragma unroll
      for (int ni = 0; ni < 4; ++ni)
        bfr[ni] = *(const bf16x8*)&Bs[(wc * 64 + ni * 16 + l16) * 64 +
                                      ((kk * 4 + kg) ^ (l16 & 7)) * 8];
#pragma unroll
      for (int mi = 0; mi < 4; ++mi)
#pragma unroll
        for (int ni = 0; ni < 4; ++ni)
          acc[mi][ni] = __builtin_amdgcn_mfma_f32_16x16x32_bf16(af[mi], bfr[ni], acc[mi][ni], 0, 0, 0);
    }
  }

  if (MODE == 1) {
    short* Cs = lds;  // 128x128 bf16 tile
    __syncthreads();  // all waves done with As/Bs
    float ps[4] = {0.f, 0.f, 0.f, 0.f};
#pragma unroll
    for (int mi = 0; mi < 4; ++mi)
#pragma unroll
      for (int ni = 0; ni < 4; ++ni) {
        const int cl = wc * 64 + ni * 16 + l16;
        const int col = ct * 128 + cl;
#pragma unroll
        for (int r = 0; r < 4; ++r) {
          const int rl = wr * 64 + kg * 4 + mi * 16 + r;
          const int row = rt * 128 + rl;
          float e = (row >= col) ? __expf(acc[mi][ni][r] * scale) : 1.0f;
          Cs[rl * 128 + cl] = f2bf(e);
          ps[ni] += e;
        }
      }
#pragma unroll
    for (int ni = 0; ni < 4; ++ni)
      atomicAdd(&csum[wc * 64 + ni * 16 + l16], ps[ni]);
    __syncthreads();
    short* C = (short*)Cg + (long)bz * sC;
    const int rr = t >> 1, cc = (t & 1) * 64;
    const long gbase = (long)(rt * 128 + rr) * N + ct * 128 + cc;
#pragma unroll
    for (int j = 0; j < 8; ++j)
      *(bf16x8*)(C + gbase + j * 8) = *(const bf16x8*)&Cs[rr * 128 + cc + j * 8];
    if (t < 128)
      atomicAdd(&colsum[(long)bz * N + ct * 128 + t], csum[t]);
  } else if (MODE == 0) {
    short* Cs = lds;
    __syncthreads();
    const int Nh = N >> 1;
#pragma unroll
    for (int mi = 0; mi < 4; ++mi)
#pragma unroll
      for (int ni = 0; ni < 4; ++ni) {
        const int cl = wc * 64 + ni * 16 + l16;
        const int colg = ct * 128 + cl;
        const float bv = (colg < Nh) ? bias[colg] : bias2[colg - Nh];
#pragma unroll
        for (int r = 0; r < 4; ++r) {
          const int rl = wr * 64 + kg * 4 + mi * 16 + r;
          Cs[rl * 128 + cl] = f2bf(acc[mi][ni][r] + bv);
        }
      }
    __syncthreads();
    short* C = (ct * 128 < Nh) ? (short*)Cg : (short*)Cg2;
    const int colofs = (ct * 128) & (Nh - 1);
    const int rr = t >> 1, cc = (t & 1) * 64;
    const long gbase = (long)(rt * 128 + rr) * Nh + colofs + cc;
#pragma unroll
    for (int j = 0; j < 8; ++j)
      *(bf16x8*)(C + gbase + j * 8) = *(const bf16x8*)&Cs[rr * 128 + cc + j * 8];
  } else {
    const int rowb = rt * 128 + wr * 64 + kg * 4;
    const int colb = ct * 128 + wc * 64 + l16;
    float* C = (float*)Cg + (long)bz * sC;
    const float* sf = sfx + ((long)bz * 16 + rt) * N;
#pragma unroll
    for (int mi = 0; mi < 4; ++mi)
#pragma unroll
      for (int ni = 0; ni < 4; ++ni) {
        int col = colb + ni * 16;
        float s = sf[col];
#pragma unroll
        for (int r = 0; r < 4; ++r) {
          int row = rowb + mi * 16 + r;
          C[(long)row * N + col] = acc[mi][ni][r] + s;  // 64B segments, no allocate
        }
      }
  }
}

// fp32 -> bf16 elementwise (n multiple of 4)
__global__ __launch_bounds__(256) void f32_to_bf16(
    const float* __restrict__ src, short* __restrict__ dst, long n)
{
  long i = ((long)blockIdx.x * blockDim.x + threadIdx.x) * 4;
  if (i < n) {
    const float4 v = *(const float4*)(src + i);
    s16x4 o;
    o.x = f2bf(v.x); o.y = f2bf(v.y); o.z = f2bf(v.z); o.w = f2bf(v.w);
    *(s16x4*)(dst + i) = o;
  }
}

// W transpose: dst[c][r] = src_z[r][c], src fp32 [E,H] -> dst bf16 [H,E].
// z = blockIdx.z picks (src0 -> dst) or (src1 -> dst + H*E).
__global__ __launch_bounds__(256) void wtrans(
    const float* __restrict__ src0, const float* __restrict__ src1,
    short* __restrict__ dst)
{
  __shared__ short tile[64][65];
  const int t = threadIdx.x;
  const int c0 = blockIdx.x * 64;   // over H (dst rows)
  const int r0 = blockIdx.y * 64;   // over E
  const float* s = blockIdx.z ? src1 : src0;
  short* d = dst + (long)blockIdx.z * H_DIM * E_DIM;
  const int rl = t >> 4, cb = (t & 15) * 4;
#pragma unroll
  for (int i = 0; i < 4; ++i) {
    int r = rl + i * 16;
    const float4 w = *(const float4*)(s + (long)(r0 + r) * H_DIM + c0 + cb);
    tile[r][cb + 0] = f2bf(w.x); tile[r][cb + 1] = f2bf(w.y);
    tile[r][cb + 2] = f2bf(w.z); tile[r][cb + 3] = f2bf(w.w);
  }
  __syncthreads();
#pragma unroll
  for (int i = 0; i < 4; ++i) {
    int rr = rl + i * 16;
    s16x4 o;
    o.x = tile[cb + 0][rr]; o.y = tile[cb + 1][rr];
    o.z = tile[cb + 2][rr]; o.w = tile[cb + 3][rr];
    *(s16x4*)(d + (long)(c0 + rr) * E_DIM + r0 + cb) = o;
  }
}

// vT[h][k] = v[k][h] / sums[k]   (v bf16 [T,H] -> vT bf16 [H,T], per batch z)
__global__ __launch_bounds__(256) void vtrans(
    const short* __restrict__ src, short* __restrict__ dst,
    const float* __restrict__ sums)
{
  __shared__ short tile[64][65];
  const int t = threadIdx.x;
  const int c0 = blockIdx.x * 64;   // over H
  const int r0 = blockIdx.y * 64;   // over T (keys)
  const int bz = blockIdx.z;
  const short* s = src + (long)bz * T_DIM * H_DIM;
  short* d = dst + (long)bz * H_DIM * T_DIM;
  const float* su = sums + (long)bz * T_DIM;
  const int rl = t >> 4, cb = (t & 15) * 4;
#pragma unroll
  for (int i = 0; i < 4; ++i) {
    int r = rl + i * 16;
    const float rs = 1.0f / su[r0 + r];
    const s16x4 w = *(const s16x4*)(s + (long)(r0 + r) * H_DIM + c0 + cb);
    tile[r][cb + 0] = f2bf(bf2f(w.x) * rs); tile[r][cb + 1] = f2bf(bf2f(w.y) * rs);
    tile[r][cb + 2] = f2bf(bf2f(w.z) * rs); tile[r][cb + 3] = f2bf(bf2f(w.w) * rs);
  }
  __syncthreads();
#pragma unroll
  for (int i = 0; i < 4; ++i) {
    int rr = rl + i * 16;
    s16x4 o;
    o.x = tile[cb + 0][rr]; o.y = tile[cb + 1][rr];
    o.z = tile[cb + 2][rr]; o.w = tile[cb + 3][rr];
    *(s16x4*)(d + (long)(c0 + rr) * T_DIM + r0 + cb) = o;
  }
}

// psum[bz][j][h2] for 2 h-columns per thread (4B loads)
__global__ __launch_bounds__(256) void block_psum(
    const short* __restrict__ v, const float* __restrict__ colsum,
    float* __restrict__ psum)
{
  const int h = (blockIdx.x * 256 + threadIdx.x) * 2;
  const int j = blockIdx.y, bz = blockIdx.z;
  const short* vb = v + (long)bz * T_DIM * H_DIM;
  const float* cs = colsum + (long)bz * T_DIM;
  float s0 = 0.f, s1 = 0.f;
  const int k0 = j * 128;
  for (int k = k0; k < k0 + 128; ++k) {
    union { int i; short s[2]; } w;
    w.i = *(const int*)(vb + (long)k * H_DIM + h);
    const float rs = 1.0f / cs[k];
    s0 += bf2f(w.s[0]) * rs;
    s1 += bf2f(w.s[1]) * rs;
  }
  float* p = psum + ((long)bz * 16 + j) * H_DIM + h;
  p[0] = s0; p[1] = s1;
}

// sfx[bz][by][h] = sum_{j > by} psum[bz][j][h]
__global__ __launch_bounds__(256) void suffix_scan(
    const float* __restrict__ psum, float* __restrict__ sfx)
{
  const int h = blockIdx.x * 256 + threadIdx.x;
  const int bz = blockIdx.z;
  const long base = (long)bz * 16 * H_DIM + h;
  float suf = 0.f;
  sfx[base + 15L * H_DIM] = 0.f;
  for (int j = 15; j >= 1; --j) {
    suf += psum[base + (long)j * H_DIM];
    sfx[base + (long)(j - 1) * H_DIM] = suf;
  }
}

extern "C" void kernel_launch(void* const* d_in, const int* in_sizes, int n_in,
                              void* d_out, int out_size, void* d_ws, size_t ws_size,
                              hipStream_t stream) {
  const float* x  = (const float*)d_in[0];
  const float* Wq = (const float*)d_in[1];
  const float* bq = (const float*)d_in[2];
  const float* Wv = (const float*)d_in[3];
  const float* bv = (const float*)d_in[4];
  float* out = (float*)d_out;

  // d_ws layout (96 MiB + 544 KiB)
  char* ws = (char*)d_ws;
  short* P      = (short*)(ws);                                   // 32 MiB [B][T][T] (lower tiles)
  short* q      = (short*)(ws + (size_t)32 * 1024 * 1024);        // 32 MiB [B*T][H]
  short* v      = (short*)(ws + (size_t)64 * 1024 * 1024);        // 32 MiB [B*T][H]
  float* colsum = (float*)(ws + (size_t)96 * 1024 * 1024);        // 32 KiB [B][T]
  float* sfx    = (float*)(ws + (size_t)96 * 1024 * 1024 + 32 * 1024);  // 512 KiB [B][16][H]
  short* vT = q;  // alias: q dead after the scores GEMM

  // d_out (64 MiB) doubles as scratch; all dead before PV GEMM writes d_out.
  short* xb    = (short*)d_out;                                     // 16 MiB [B*T][E]
  short* WqvT  = (short*)((char*)d_out + (size_t)16 * 1024 * 1024); //  8 MiB [2H][E]
  float* psum  = (float*)((char*)d_out + (size_t)24 * 1024 * 1024); // 512 KiB [B][16][H]

  const float scale = 0.022097086912079612f;  // 1/sqrt(2048)
  dim3 blk(256);

  hipMemsetAsync(colsum, 0, (size_t)B_DIM * T_DIM * 4, stream);

  // x -> bf16; Wq|Wv -> transposed bf16 [2H][E] (one launch, z picks matrix)
  f32_to_bf16<<<dim3((B_DIM * T_DIM * E_DIM) / (256 * 4)), blk, 0, stream>>>(
      x, xb, (long)B_DIM * T_DIM * E_DIM);
  wtrans<<<dim3(H_DIM / 64, E_DIM / 64, 2), blk, 0, stream>>>(Wq, Wv, WqvT);

  // fused projections: [q | v] = x @ WqvT^T + [bq | bv]  (M=8192, N=4096, K=1024)
  gemm_bt<0><<<dim3((2 * H_DIM) / 128, (B_DIM * T_DIM) / 128, 1), blk, 0, stream>>>(
      xb, WqvT, bq, bv, q, v, nullptr, nullptr,
      B_DIM * T_DIM, 2 * H_DIM, E_DIM, 0, 0, 0, 1.f);

  // E = exp(mask(q q^T)/sqrt(H)): lower-triangular tiles + colsum (diag-seeded)
  gemm_bt<1><<<dim3(136, 1, B_DIM), blk, 0, stream>>>(
      q, q, nullptr, nullptr, P, nullptr, colsum, nullptr, T_DIM, T_DIM, H_DIM,
      (long)T_DIM * H_DIM, (long)T_DIM * H_DIM, (long)T_DIM * T_DIM, scale);

  // vT[h][k] = v[k][h] / colsum[k]; suffix sums of v' over key blocks
  vtrans<<<dim3(H_DIM / 64, T_DIM / 64, B_DIM), blk, 0, stream>>>(v, vT, colsum);
  block_psum<<<dim3(H_DIM / 512, 16, B_DIM), blk, 0, stream>>>(v, colsum, psum);
  suffix_scan<<<dim3(H_DIM / 256, 1, B_DIM), blk, 0, stream>>>(psum, sfx);

  // out = P(:, :K_end) @ v'(:K_end, :) + sfx[rt]   (M=T, N=H, K=T) per batch
  gemm_bt<2><<<dim3(T_DIM / 128, H_DIM / 128, B_DIM), blk, 0, stream>>>(
      P, vT, nullptr, nullptr, out, nullptr, nullptr, sfx, T_DIM, H_DIM, T_DIM,
      (long)T_DIM * T_DIM, (long)H_DIM * T_DIM, (long)T_DIM * H_DIM, 1.f);
}